// Round 1
// baseline (402.666 us; speedup 1.0000x reference)
//
#include <hip/hip_runtime.h>
#include <hip/hip_bf16.h>

typedef __hip_bfloat16 bf16;
typedef float f32x4 __attribute__((ext_vector_type(4)));
typedef short bf16x8 __attribute__((ext_vector_type(8)));

#define B_   2
#define S_   2048
#define DM   2048
#define HD   64
#define NH   32

// async global->LDS, 16B per lane; dest must be wave-uniform base (+lane*16 auto)
__device__ __forceinline__ void async16(void* lds, const void* g) {
  __builtin_amdgcn_global_load_lds(
      (const __attribute__((address_space(1))) unsigned int*)g,
      (__attribute__((address_space(3))) unsigned int*)lds, 16, 0, 0);
}

// ---------------- fp32 -> bf16, 8 elems/thread ----------------
__global__ void cvt_bf16_kernel(const float* __restrict__ in, bf16* __restrict__ out, int n) {
  int i = (blockIdx.x * blockDim.x + threadIdx.x) * 8;
  if (i >= n) return;
  float4 a = *(const float4*)(in + i);
  float4 b = *(const float4*)(in + i + 4);
  union { bf16 h[8]; uint4 v; } u;
  u.h[0] = __float2bfloat16(a.x); u.h[1] = __float2bfloat16(a.y);
  u.h[2] = __float2bfloat16(a.z); u.h[3] = __float2bfloat16(a.w);
  u.h[4] = __float2bfloat16(b.x); u.h[5] = __float2bfloat16(b.y);
  u.h[6] = __float2bfloat16(b.z); u.h[7] = __float2bfloat16(b.w);
  *(uint4*)(out + i) = u.v;
}

// ---------------- Wt[n][k] = (bf16) W[k][n], LDS-tiled ----------------
__global__ void transpose_cvt_kernel(const float* __restrict__ W, bf16* __restrict__ Wt,
                                     int K, int N) {
  __shared__ float tile[32][33];
  int k0 = blockIdx.x * 32, n0 = blockIdx.y * 32;
  int tx = threadIdx.x, ty = threadIdx.y;
  #pragma unroll
  for (int i = 0; i < 32; i += 8)
    tile[ty + i][tx] = W[(size_t)(k0 + ty + i) * N + n0 + tx];
  __syncthreads();
  #pragma unroll
  for (int i = 0; i < 32; i += 8)
    Wt[(size_t)(n0 + ty + i) * K + k0 + tx] = __float2bfloat16(tile[tx][ty + i]);
}

__global__ void concat_bias_kernel(const float* __restrict__ bk, const float* __restrict__ bv,
                                   float* __restrict__ out) {
  int i = blockIdx.x * blockDim.x + threadIdx.x;
  if (i < 1024) out[i] = (i < 512) ? bk[i] : bv[i - 512];
}

__device__ __forceinline__ void store_out(float* C, size_t idx, float v) { C[idx] = v; }
__device__ __forceinline__ void store_out(bf16* C, size_t idx, float v) { C[idx] = __float2bfloat16(v); }

// ---------------- GEMM: C[M][N] = A[M][K] @ Bt[N][K]^T + bias ----------------
// 128x128 tile, BK=32, 4 waves (2x2), 16x16x32 bf16 MFMA, global_load_lds width-16,
// inverse-swizzled source + swizzled read (rule #21), 2-phase LDS double buffer.
// A-pointer switches to A2 for n0 >= nsplit (used to fuse the K/V projections).
template <typename OUT>
__global__ __launch_bounds__(256)
void gemm_bt_bias(const bf16* __restrict__ A, const bf16* __restrict__ A2, int nsplit,
                  const bf16* __restrict__ Bt, const float* __restrict__ bias,
                  OUT* __restrict__ C, int M, int N, int K) {
  constexpr int BM = 128, BK = 32;
  __shared__ __align__(16) bf16 As[2][BM * BK];
  __shared__ __align__(16) bf16 Bs[2][BM * BK];
  const int tid = threadIdx.x;
  const int wave = tid >> 6, lane = tid & 63;
  const int l15 = lane & 15, l4 = lane >> 4;
  const int m0 = blockIdx.x * BM, n0 = blockIdx.y * BM;
  const bf16* Au = (n0 < nsplit) ? A : A2;
  const int wm = (wave & 1) * 64, wn = (wave >> 1) * 64;

  f32x4 acc[4][4] = {};
  const int nk = K / BK;

  auto stage = [&](int kt, int buf) {
    const int k0 = kt * BK;
    #pragma unroll
    for (int i = 0; i < 2; ++i) {
      const int rb = wave * 32 + i * 16;          // 16 rows per instruction
      const int r  = rb + (lane >> 2);
      const int cs = (lane & 3) ^ ((r >> 1) & 3); // inverse chunk swizzle
      async16(&As[buf][rb * BK], Au + (size_t)(m0 + r) * K + k0 + cs * 8);
      async16(&Bs[buf][rb * BK], Bt + (size_t)(n0 + r) * K + k0 + cs * 8);
    }
  };

  stage(0, 0);
  asm volatile("s_waitcnt vmcnt(0)" ::: "memory");
  __syncthreads();

  for (int kt = 0; kt < nk; ++kt) {
    const int cur = kt & 1;
    if (kt + 1 < nk) stage(kt + 1, cur ^ 1);
    bf16x8 af[4], bfr[4];
    #pragma unroll
    for (int f = 0; f < 4; ++f) {
      const int mr = wm + f * 16 + l15;
      af[f]  = *(const bf16x8*)(&As[cur][mr * BK + (l4 ^ ((mr >> 1) & 3)) * 8]);
      const int nr = wn + f * 16 + l15;
      bfr[f] = *(const bf16x8*)(&Bs[cur][nr * BK + (l4 ^ ((nr >> 1) & 3)) * 8]);
    }
    #pragma unroll
    for (int i = 0; i < 4; ++i)
      #pragma unroll
      for (int j = 0; j < 4; ++j)
        acc[i][j] = __builtin_amdgcn_mfma_f32_16x16x32_bf16(af[i], bfr[j], acc[i][j], 0, 0, 0);
    asm volatile("s_waitcnt vmcnt(0)" ::: "memory");
    __syncthreads();
  }

  const int r0 = m0 + wm + l4 * 4;
  const int c0 = n0 + wn + l15;
  #pragma unroll
  for (int j = 0; j < 4; ++j) {
    const int col = c0 + j * 16;
    const float bb = bias[col];
    #pragma unroll
    for (int i = 0; i < 4; ++i)
      #pragma unroll
      for (int r = 0; r < 4; ++r)
        store_out(C, (size_t)(r0 + i * 16 + r) * N + col, acc[i][j][r] + bb);
  }
}

// ---------------- causal GQA flash attention ----------------
// grid (qt=32, h=32, b=2), 256 threads = 4 waves, 16 q-rows per wave, KV tile 64.
// Q [B*S][2048] bf16 ; KV [B*S][1024] bf16 (cols 0..511 = K heads, 512..1023 = V heads)
__global__ __launch_bounds__(256)
void attn_kernel(const bf16* __restrict__ Q, const bf16* __restrict__ KV, bf16* __restrict__ O) {
  const int qt = blockIdx.x, h = blockIdx.y, b = blockIdx.z;
  const int g = h >> 2;
  const int tid = threadIdx.x;
  const int wave = tid >> 6, lane = tid & 63;
  const int l15 = lane & 15, l4 = lane >> 4;

  __shared__ __align__(16) bf16 Ks[64 * 64];      // [kv][d], XOR-swizzled chunks
  __shared__ __align__(16) bf16 Vt[64 * 64];      // [d][kv], XOR-swizzled chunks
  __shared__ __align__(16) bf16 Pw[4][16 * 72];   // per-wave P tile, padded rows

  // Q fragments held in registers for the whole kernel
  const size_t qrow = (size_t)(b * S_ + qt * 64 + wave * 16 + l15);
  const bf16* qp = Q + qrow * DM + h * HD + l4 * 8;
  const bf16x8 qf0 = *(const bf16x8*)(qp);
  const bf16x8 qf1 = *(const bf16x8*)(qp + 32);

  f32x4 acc[4] = {};
  float mrow[4], lrow[4];
  #pragma unroll
  for (int r = 0; r < 4; ++r) { mrow[r] = -INFINITY; lrow[r] = 0.f; }
  const float scale = 0.04419417382415922f;   // 1/sqrt(512) per reference

  const int kv2 = tid & 31;         // V staging: kv row pair
  const int d0  = (tid >> 5) * 8;   // V staging: d chunk

  for (int kt = 0; kt <= qt; ++kt) {
    const int kv0 = kt * 64;
    // stage K: global_load_lds, inverse-swizzled source
    #pragma unroll
    for (int i = 0; i < 2; ++i) {
      const int rb = wave * 16 + i * 8;
      const int r  = rb + (lane >> 3);
      const int cs = (lane & 7) ^ (r & 7);
      async16(&Ks[rb * 64], KV + (size_t)(b * S_ + kv0 + r) * 1024 + g * HD + cs * 8);
    }
    // stage V transposed (reg-staged), swizzled b32 writes
    {
      const bf16* vp = KV + (size_t)(b * S_ + kv0 + 2 * kv2) * 1024 + 512 + g * HD + d0;
      uint4 v0 = *(const uint4*)(vp);
      uint4 v1 = *(const uint4*)(vp + 1024);
      const unsigned short* a0 = (const unsigned short*)&v0;
      const unsigned short* a1 = (const unsigned short*)&v1;
      #pragma unroll
      for (int j = 0; j < 8; ++j) {
        unsigned val = (unsigned)a0[j] | ((unsigned)a1[j] << 16);
        const int byte = (d0 + j) * 128 + ((kv2 * 4) ^ (j << 4));
        *(unsigned*)((char*)Vt + byte) = val;
      }
    }
    asm volatile("s_waitcnt vmcnt(0)" ::: "memory");
    __syncthreads();

    // S = Q K^T  (4 col-fragments of 16 kv each)
    f32x4 s[4];
    #pragma unroll
    for (int c = 0; c < 4; ++c) {
      const int kvr = c * 16 + l15;
      const int sw = (kvr & 7) << 4;
      const char* kbase = (const char*)Ks + kvr * 128;
      bf16x8 kb0 = *(const bf16x8*)(kbase + ((l4 * 16) ^ sw));
      bf16x8 kb1 = *(const bf16x8*)(kbase + ((64 + l4 * 16) ^ sw));
      f32x4 z = {0.f, 0.f, 0.f, 0.f};
      z = __builtin_amdgcn_mfma_f32_16x16x32_bf16(qf0, kb0, z, 0, 0, 0);
      z = __builtin_amdgcn_mfma_f32_16x16x32_bf16(qf1, kb1, z, 0, 0, 0);
      s[c] = z;
    }

    // scale + causal mask + wave-parallel online softmax
    const int mb = l4 * 4;          // row-within-wave-tile base
    float pmax[4];
    #pragma unroll
    for (int r = 0; r < 4; ++r) pmax[r] = -INFINITY;
    const bool diag = (kt == qt);
    #pragma unroll
    for (int c = 0; c < 4; ++c)
      #pragma unroll
      for (int r = 0; r < 4; ++r) {
        float v = s[c][r] * scale;
        if (diag && (c * 16 + l15) > (wave * 16 + mb + r)) v = -INFINITY;
        s[c][r] = v;
        pmax[r] = fmaxf(pmax[r], v);
      }
    #pragma unroll
    for (int r = 0; r < 4; ++r) {
      float t = pmax[r];
      t = fmaxf(t, __shfl_xor(t, 1));
      t = fmaxf(t, __shfl_xor(t, 2));
      t = fmaxf(t, __shfl_xor(t, 4));
      t = fmaxf(t, __shfl_xor(t, 8));
      pmax[r] = t;
    }
    float alpha[4], rs[4];
    #pragma unroll
    for (int r = 0; r < 4; ++r) {
      const float mn = fmaxf(mrow[r], pmax[r]);
      alpha[r] = __expf(mrow[r] - mn);   // first tile: exp(-inf)=0
      mrow[r] = mn;
      rs[r] = 0.f;
    }
    // P = exp(s - m) -> per-wave LDS tile (bf16)
    #pragma unroll
    for (int c = 0; c < 4; ++c)
      #pragma unroll
      for (int r = 0; r < 4; ++r) {
        const float p = __expf(s[c][r] - mrow[r]);
        rs[r] += p;
        Pw[wave][(mb + r) * 72 + c * 16 + l15] = __float2bfloat16(p);
      }
    #pragma unroll
    for (int r = 0; r < 4; ++r) {
      float t = rs[r];
      t += __shfl_xor(t, 1);
      t += __shfl_xor(t, 2);
      t += __shfl_xor(t, 4);
      t += __shfl_xor(t, 8);
      lrow[r] = lrow[r] * alpha[r] + t;
    }
    #pragma unroll
    for (int c = 0; c < 4; ++c)
      #pragma unroll
      for (int r = 0; r < 4; ++r)
        acc[c][r] *= alpha[r];

    // PV (wave-local P through LDS; fence writes before cross-lane reads)
    asm volatile("s_waitcnt lgkmcnt(0)" ::: "memory");
    #pragma unroll
    for (int kk = 0; kk < 2; ++kk) {
      const bf16x8 pa = *(const bf16x8*)(&Pw[wave][l15 * 72 + kk * 32 + l4 * 8]);
      #pragma unroll
      for (int c = 0; c < 4; ++c) {
        const int dd = c * 16 + l15;
        const bf16x8 vb = *(const bf16x8*)((const char*)Vt + dd * 128 +
                                           ((kk * 64 + l4 * 16) ^ ((dd & 7) << 4)));
        acc[c] = __builtin_amdgcn_mfma_f32_16x16x32_bf16(pa, vb, acc[c], 0, 0, 0);
      }
    }
    __syncthreads();   // all waves done reading Ks/Vt before next stage
  }

  const size_t orow = (size_t)(b * S_ + qt * 64 + wave * 16 + l4 * 4);
  #pragma unroll
  for (int c = 0; c < 4; ++c) {
    const int col = h * HD + c * 16 + l15;
    #pragma unroll
    for (int r = 0; r < 4; ++r)
      O[(orow + r) * DM + col] = __float2bfloat16(acc[c][r] / lrow[r]);
  }
}

extern "C" void kernel_launch(void* const* d_in, const int* in_sizes, int n_in,
                              void* d_out, int out_size, void* d_ws, size_t ws_size,
                              hipStream_t stream) {
  const float* xq = (const float*)d_in[0];
  const float* xk = (const float*)d_in[1];
  const float* xv = (const float*)d_in[2];
  const float* Wq = (const float*)d_in[3];
  const float* bq = (const float*)d_in[4];
  const float* Wk = (const float*)d_in[5];
  const float* bk = (const float*)d_in[6];
  const float* Wv = (const float*)d_in[7];
  const float* bv = (const float*)d_in[8];
  const float* Wo = (const float*)d_in[9];
  const float* bo = (const float*)d_in[10];
  float* out = (float*)d_out;

  char* ws = (char*)d_ws;
  // workspace layout (bytes); total 96,473,088
  bf16*  Xq   = (bf16*)(ws);                    // 16,777,216  (reused as AO later)
  bf16*  Xk   = (bf16*)(ws + 16777216);         // 16,777,216
  bf16*  Xv   = (bf16*)(ws + 33554432);         // 16,777,216
  bf16*  WqT  = (bf16*)(ws + 50331648);         //  8,388,608
  bf16*  WkvT = (bf16*)(ws + 58720256);         //  4,194,304
  bf16*  WoT  = (bf16*)(ws + 62914560);         //  8,388,608
  float* bkv  = (float*)(ws + 71303168);        //      4,096
  bf16*  Qb   = (bf16*)(ws + 71307264);         // 16,777,216
  bf16*  KVb  = (bf16*)(ws + 88084480);         //  8,388,608
  bf16*  AO   = Xq;  // Xq is dead after the Q projection

  const int NEL = 4096 * 2048;
  cvt_bf16_kernel<<<4096, 256, 0, stream>>>(xq, Xq, NEL);
  cvt_bf16_kernel<<<4096, 256, 0, stream>>>(xk, Xk, NEL);
  cvt_bf16_kernel<<<4096, 256, 0, stream>>>(xv, Xv, NEL);
  transpose_cvt_kernel<<<dim3(64, 64), dim3(32, 8), 0, stream>>>(Wq, WqT, 2048, 2048);
  transpose_cvt_kernel<<<dim3(64, 16), dim3(32, 8), 0, stream>>>(Wk, WkvT, 2048, 512);
  transpose_cvt_kernel<<<dim3(64, 16), dim3(32, 8), 0, stream>>>(Wv, WkvT + (size_t)512 * 2048, 2048, 512);
  transpose_cvt_kernel<<<dim3(64, 64), dim3(32, 8), 0, stream>>>(Wo, WoT, 2048, 2048);
  concat_bias_kernel<<<4, 256, 0, stream>>>(bk, bv, bkv);

  // Q projection: [4096,2048] @ WqT^T
  gemm_bt_bias<bf16><<<dim3(32, 16), 256, 0, stream>>>(Xq, Xq, 1 << 30, WqT, bq, Qb, 4096, 2048, 2048);
  // fused K|V projection: N=1024, A switches Xk->Xv at n=512
  gemm_bt_bias<bf16><<<dim3(32, 8), 256, 0, stream>>>(Xk, Xv, 512, WkvT, bkv, KVb, 4096, 1024, 2048);
  // causal GQA attention
  attn_kernel<<<dim3(32, 32, 2), 256, 0, stream>>>(Qb, KVb, AO);
  // output projection -> fp32 out
  gemm_bt_bias<float><<<dim3(32, 16), 256, 0, stream>>>(AO, AO, 1 << 30, WoT, bo, out, 4096, 2048, 2048);
}

// Round 2
// 267.842 us; speedup vs baseline: 1.5034x; 1.5034x over previous
//
#include <hip/hip_runtime.h>
#include <hip/hip_bf16.h>

typedef __hip_bfloat16 bf16;
typedef float f32x4 __attribute__((ext_vector_type(4)));
typedef float f32x16 __attribute__((ext_vector_type(16)));
typedef short bf16x8 __attribute__((ext_vector_type(8)));

#define B_   2
#define S_   2048
#define DM   2048
#define HD   64
#define NH   32

// async global->LDS, 16B per lane; dest must be wave-uniform base (+lane*16 auto)
__device__ __forceinline__ void async16(void* lds, const void* g) {
  __builtin_amdgcn_global_load_lds(
      (const __attribute__((address_space(1))) unsigned int*)g,
      (__attribute__((address_space(3))) unsigned int*)lds, 16, 0, 0);
}

__device__ __forceinline__ float exp2a(float x) {
  float r; asm("v_exp_f32 %0, %1" : "=v"(r) : "v"(x)); return r;
}
__device__ __forceinline__ unsigned cvtpk(float lo, float hi) {
  unsigned r; asm("v_cvt_pk_bf16_f32 %0, %1, %2" : "=v"(r) : "v"(lo), "v"(hi)); return r;
}
__device__ __forceinline__ void perm32swap(unsigned &a, unsigned &b) {
  asm volatile("v_permlane32_swap_b32 %0, %1" : "+v"(a), "+v"(b));
}

// ---------------- fp32 -> bf16, 8 elems/thread ----------------
__global__ void cvt_bf16_kernel(const float* __restrict__ in, bf16* __restrict__ out, int n) {
  int i = (blockIdx.x * blockDim.x + threadIdx.x) * 8;
  if (i >= n) return;
  float4 a = *(const float4*)(in + i);
  float4 b = *(const float4*)(in + i + 4);
  union { bf16 h[8]; uint4 v; } u;
  u.h[0] = __float2bfloat16(a.x); u.h[1] = __float2bfloat16(a.y);
  u.h[2] = __float2bfloat16(a.z); u.h[3] = __float2bfloat16(a.w);
  u.h[4] = __float2bfloat16(b.x); u.h[5] = __float2bfloat16(b.y);
  u.h[6] = __float2bfloat16(b.z); u.h[7] = __float2bfloat16(b.w);
  *(uint4*)(out + i) = u.v;
}

// ---------------- Wt[n][k] = (bf16) W[k][n], LDS-tiled ----------------
__global__ void transpose_cvt_kernel(const float* __restrict__ W, bf16* __restrict__ Wt,
                                     int K, int N) {
  __shared__ float tile[32][33];
  int k0 = blockIdx.x * 32, n0 = blockIdx.y * 32;
  int tx = threadIdx.x, ty = threadIdx.y;
  #pragma unroll
  for (int i = 0; i < 32; i += 8)
    tile[ty + i][tx] = W[(size_t)(k0 + ty + i) * N + n0 + tx];
  __syncthreads();
  #pragma unroll
  for (int i = 0; i < 32; i += 8)
    Wt[(size_t)(n0 + ty + i) * K + k0 + tx] = __float2bfloat16(tile[tx][ty + i]);
}

__global__ void concat_bias_kernel(const float* __restrict__ bk, const float* __restrict__ bv,
                                   float* __restrict__ out) {
  int i = blockIdx.x * blockDim.x + threadIdx.x;
  if (i < 1024) out[i] = (i < 512) ? bk[i] : bv[i - 512];
}

__device__ __forceinline__ void store_out(float* C, size_t idx, float v) { C[idx] = v; }
__device__ __forceinline__ void store_out(bf16* C, size_t idx, float v) { C[idx] = __float2bfloat16(v); }

// ---------------- GEMM: C[M][N] = (A[M][K] @ Bt[N][K]^T + bias) * omul ----------------
template <typename OUT>
__global__ __launch_bounds__(256)
void gemm_bt_bias(const bf16* __restrict__ A, const bf16* __restrict__ A2, int nsplit,
                  const bf16* __restrict__ Bt, const float* __restrict__ bias, float omul,
                  OUT* __restrict__ C, int M, int N, int K) {
  constexpr int BM = 128, BK = 32;
  __shared__ __align__(16) bf16 As[2][BM * BK];
  __shared__ __align__(16) bf16 Bs[2][BM * BK];
  const int tid = threadIdx.x;
  const int wave = tid >> 6, lane = tid & 63;
  const int l15 = lane & 15, l4 = lane >> 4;
  const int m0 = blockIdx.x * BM, n0 = blockIdx.y * BM;
  const bf16* Au = (n0 < nsplit) ? A : A2;
  const int wm = (wave & 1) * 64, wn = (wave >> 1) * 64;

  f32x4 acc[4][4] = {};
  const int nk = K / BK;

  auto stage = [&](int kt, int buf) {
    const int k0 = kt * BK;
    #pragma unroll
    for (int i = 0; i < 2; ++i) {
      const int rb = wave * 32 + i * 16;
      const int r  = rb + (lane >> 2);
      const int cs = (lane & 3) ^ ((r >> 1) & 3);
      async16(&As[buf][rb * BK], Au + (size_t)(m0 + r) * K + k0 + cs * 8);
      async16(&Bs[buf][rb * BK], Bt + (size_t)(n0 + r) * K + k0 + cs * 8);
    }
  };

  stage(0, 0);
  asm volatile("s_waitcnt vmcnt(0)" ::: "memory");
  __syncthreads();

  for (int kt = 0; kt < nk; ++kt) {
    const int cur = kt & 1;
    if (kt + 1 < nk) stage(kt + 1, cur ^ 1);
    bf16x8 af[4], bfr[4];
    #pragma unroll
    for (int f = 0; f < 4; ++f) {
      const int mr = wm + f * 16 + l15;
      af[f]  = *(const bf16x8*)(&As[cur][mr * BK + (l4 ^ ((mr >> 1) & 3)) * 8]);
      const int nr = wn + f * 16 + l15;
      bfr[f] = *(const bf16x8*)(&Bs[cur][nr * BK + (l4 ^ ((nr >> 1) & 3)) * 8]);
    }
    #pragma unroll
    for (int i = 0; i < 4; ++i)
      #pragma unroll
      for (int j = 0; j < 4; ++j)
        acc[i][j] = __builtin_amdgcn_mfma_f32_16x16x32_bf16(af[i], bfr[j], acc[i][j], 0, 0, 0);
    asm volatile("s_waitcnt vmcnt(0)" ::: "memory");
    __syncthreads();
  }

  const int r0 = m0 + wm + l4 * 4;
  const int c0 = n0 + wn + l15;
  #pragma unroll
  for (int j = 0; j < 4; ++j) {
    const int col = c0 + j * 16;
    const float bb = bias[col];
    #pragma unroll
    for (int i = 0; i < 4; ++i)
      #pragma unroll
      for (int r = 0; r < 4; ++r)
        store_out(C, (size_t)(r0 + i * 16 + r) * N + col, (acc[i][j][r] + bb) * omul);
  }
}

// ---------------- causal GQA flash attention (32x32 swapped-operand) ----------------
// grid (pair=8, h=32, b=2), 256 thr = 4 waves; wave = 32 q-rows; block = 128 q-rows.
// Block processes q-tiles `pair` and `15-pair` sequentially (constant 34 KV tiles).
// Q pre-scaled by 1/sqrt(512)*log2(e) in the Q-projection -> softmax in exp2 domain.
__global__ __launch_bounds__(256, 3)
void attn_kernel(const bf16* __restrict__ Q, const bf16* __restrict__ KV, bf16* __restrict__ O) {
  const int pair = blockIdx.x, h = blockIdx.y, b = blockIdx.z;
  const int g = h >> 2;
  const int tid = threadIdx.x;
  const int wave = tid >> 6, lane = tid & 63;
  const int l31 = lane & 31, l5 = lane >> 5;

  __shared__ __align__(16) bf16 Ks[2][64 * 64];   // [kv][d], chunk-XOR swizzled
  __shared__ __align__(16) bf16 Vt[2][64 * 64];   // [d][kv], chunk-XOR swizzled
  __shared__ __align__(16) bf16 Ost[4][32 * 72];  // per-wave O staging, 144B row stride

  const bf16* KVb = KV + (size_t)(b * S_) * 1024;
  const int kcol = g * HD;
  const int vcol = 512 + g * HD;
  const int kv2 = tid & 31, vd0 = (tid >> 5) * 8;   // V-staging mapping

  for (int sub = 0; sub < 2; ++sub) {
    const int qt = (sub == 0) ? pair : 15 - pair;
    const int qbase = qt * 128;
    const int nt = 2 * qt + 2;
    const int qrow = qbase + wave * 32 + l31;
    const int wmax = qbase + wave * 32 + 31;

    // Q fragments (B-operand layout: n=q=l31, k = ks*16 + l5*8 + j)
    bf16x8 qf[4];
    const bf16* qp = Q + (size_t)(b * S_ + qrow) * DM + h * HD + l5 * 8;
    #pragma unroll
    for (int ks = 0; ks < 4; ++ks) qf[ks] = *(const bf16x8*)(qp + ks * 16);

    f32x16 ot[2] = {};
    float m = -3.0e38f, lsum = 0.f;
    uint4 vr0, vr1;

    // ---- prologue: stage tile 0
    #pragma unroll
    for (int i2 = 0; i2 < 2; ++i2) {
      const int rb = wave * 16 + i2 * 8;
      const int r = rb + (lane >> 3);
      const int cs = (lane & 7) ^ (r & 7);
      async16(&Ks[0][rb * 64], KVb + (size_t)r * 1024 + kcol + cs * 8);
    }
    {
      const bf16* vp = KVb + (size_t)(2 * kv2) * 1024 + vcol + vd0;
      vr0 = *(const uint4*)vp;
      vr1 = *(const uint4*)(vp + 1024);
    }
    asm volatile("s_waitcnt vmcnt(0)" ::: "memory");
    {
      const unsigned short* a0 = (const unsigned short*)&vr0;
      const unsigned short* a1 = (const unsigned short*)&vr1;
      char* vb = (char*)Vt[0];
      #pragma unroll
      for (int j = 0; j < 8; ++j) {
        unsigned val = (unsigned)a0[j] | ((unsigned)a1[j] << 16);
        const int d = vd0 + j;
        *(unsigned*)(vb + d * 128 + ((kv2 * 4) ^ ((d & 7) << 4))) = val;
      }
    }
    __syncthreads();

    // ---- main KV-tile loop
    for (int t = 0; t < nt; ++t) {
      const int cur = t & 1;
      const int kv0 = t * 64;
      if (t + 1 < nt) {
        const int kvn = (t + 1) * 64;
        #pragma unroll
        for (int i2 = 0; i2 < 2; ++i2) {
          const int rb = wave * 16 + i2 * 8;
          const int r = rb + (lane >> 3);
          const int cs = (lane & 7) ^ (r & 7);
          async16(&Ks[cur ^ 1][rb * 64], KVb + (size_t)(kvn + r) * 1024 + kcol + cs * 8);
        }
        const bf16* vp = KVb + (size_t)(kvn + 2 * kv2) * 1024 + vcol + vd0;
        vr0 = *(const uint4*)vp;
        vr1 = *(const uint4*)(vp + 1024);
      }

      if (kv0 <= wmax) {   // wave-uniform compute-skip
        // S^T = K @ Q^T : lane owns q-col l31; kv rows per C-layout
        f32x16 sT[2] = {};
        #pragma unroll
        for (int ks = 0; ks < 4; ++ks) {
          #pragma unroll
          for (int i = 0; i < 2; ++i) {
            const int row = i * 32 + l31;
            bf16x8 kf = *(const bf16x8*)((const char*)Ks[cur] + row * 128 +
                                         ((ks * 32 + l5 * 16) ^ ((row & 7) << 4)));
            sT[i] = __builtin_amdgcn_mfma_f32_32x32x16_bf16(kf, qf[ks], sT[i], 0, 0, 0);
          }
        }
        // causal mask (only tiles overlapping the diagonal for this wave)
        if (kv0 + 63 > qbase + wave * 32) {
          #pragma unroll
          for (int i = 0; i < 2; ++i)
            #pragma unroll
            for (int r = 0; r < 16; ++r) {
              const int kvg = kv0 + i * 32 + ((r & 3) + 8 * (r >> 2)) + 4 * l5;
              if (kvg > qrow) sT[i][r] = -3.0e38f;
            }
        }
        // row max: tree over own 32 + partner half via xor-32
        float a16[16];
        #pragma unroll
        for (int r = 0; r < 16; ++r) a16[r] = fmaxf(sT[0][r], sT[1][r]);
        #pragma unroll
        for (int s2 = 8; s2 >= 1; s2 >>= 1)
          #pragma unroll
          for (int r = 0; r < 8; ++r) if (r < s2) a16[r] = fmaxf(a16[r], a16[r + s2]);
        float pm = fmaxf(a16[0], __shfl_xor(a16[0], 32));
        const float mn = fmaxf(m, pm);
        const float alpha = exp2a(m - mn);
        m = mn;
        // P = exp2(s - m), pack to bf16 pairs
        float rs0 = 0.f, rs1 = 0.f;
        unsigned pk[2][8];
        #pragma unroll
        for (int i = 0; i < 2; ++i)
          #pragma unroll
          for (int rr = 0; rr < 8; ++rr) {
            const float p0 = exp2a(sT[i][2 * rr] - mn);
            const float p1 = exp2a(sT[i][2 * rr + 1] - mn);
            if (i == 0) rs0 += p0 + p1; else rs1 += p0 + p1;
            pk[i][rr] = cvtpk(p0, p1);
          }
        float rs = rs0 + rs1;
        rs += __shfl_xor(rs, 32);
        lsum = lsum * alpha + rs;
        #pragma unroll
        for (int r = 0; r < 16; ++r) { ot[0][r] *= alpha; ot[1][r] *= alpha; }
        // PV: build P fragments in-register via permlane32_swap, accumulate O^T
        #pragma unroll
        for (int i = 0; i < 2; ++i) {
          #pragma unroll
          for (int kp = 0; kp < 2; ++kp) {
            unsigned w0 = pk[i][4 * kp + 0], w1 = pk[i][4 * kp + 1];
            unsigned w2 = pk[i][4 * kp + 2], w3 = pk[i][4 * kp + 3];
            perm32swap(w0, w2);
            perm32swap(w1, w3);
            union { unsigned u[4]; bf16x8 v; } pf = {{w0, w1, w2, w3}};
            const int ks2 = i * 2 + kp;
            #pragma unroll
            for (int f = 0; f < 2; ++f) {
              const int row = f * 32 + l31;
              bf16x8 vf = *(const bf16x8*)((const char*)Vt[cur] + row * 128 +
                                           ((ks2 * 32 + l5 * 16) ^ ((row & 7) << 4)));
              ot[f] = __builtin_amdgcn_mfma_f32_32x32x16_bf16(vf, pf.v, ot[f], 0, 0, 0);
            }
          }
        }
      }

      asm volatile("s_waitcnt vmcnt(0)" ::: "memory");
      if (t + 1 < nt) {
        const unsigned short* a0 = (const unsigned short*)&vr0;
        const unsigned short* a1 = (const unsigned short*)&vr1;
        char* vb = (char*)Vt[cur ^ 1];
        #pragma unroll
        for (int j = 0; j < 8; ++j) {
          unsigned val = (unsigned)a0[j] | ((unsigned)a1[j] << 16);
          const int d = vd0 + j;
          *(unsigned*)(vb + d * 128 + ((kv2 * 4) ^ ((d & 7) << 4))) = val;
        }
      }
      __syncthreads();
    }

    // ---- epilogue: O^T/l -> per-wave LDS tile -> coalesced global store
    const float inv = 1.0f / lsum;
    char* ob = (char*)&Ost[wave][0];
    #pragma unroll
    for (int f = 0; f < 2; ++f)
      #pragma unroll
      for (int g2 = 0; g2 < 4; ++g2) {
        uint2 val;
        val.x = cvtpk(ot[f][g2 * 4 + 0] * inv, ot[f][g2 * 4 + 1] * inv);
        val.y = cvtpk(ot[f][g2 * 4 + 2] * inv, ot[f][g2 * 4 + 3] * inv);
        *(uint2*)(ob + l31 * 144 + f * 64 + g2 * 16 + l5 * 8) = val;
      }
    asm volatile("s_waitcnt lgkmcnt(0)" ::: "memory");
    __builtin_amdgcn_sched_barrier(0);
    #pragma unroll
    for (int rr = 0; rr < 4; ++rr) {
      const int row = rr * 8 + (lane >> 3);
      uint4 dv = *(const uint4*)(ob + row * 144 + (lane & 7) * 16);
      *(uint4*)(O + (size_t)(b * S_ + qbase + wave * 32 + row) * DM + h * HD + (lane & 7) * 8) = dv;
    }
  }
}

extern "C" void kernel_launch(void* const* d_in, const int* in_sizes, int n_in,
                              void* d_out, int out_size, void* d_ws, size_t ws_size,
                              hipStream_t stream) {
  const float* xq = (const float*)d_in[0];
  const float* xk = (const float*)d_in[1];
  const float* xv = (const float*)d_in[2];
  const float* Wq = (const float*)d_in[3];
  const float* bq = (const float*)d_in[4];
  const float* Wk = (const float*)d_in[5];
  const float* bk = (const float*)d_in[6];
  const float* Wv = (const float*)d_in[7];
  const float* bv = (const float*)d_in[8];
  const float* Wo = (const float*)d_in[9];
  const float* bo = (const float*)d_in[10];
  float* out = (float*)d_out;

  char* ws = (char*)d_ws;
  bf16*  Xq   = (bf16*)(ws);                    // 16,777,216  (reused as AO later)
  bf16*  Xk   = (bf16*)(ws + 16777216);         // 16,777,216
  bf16*  Xv   = (bf16*)(ws + 33554432);         // 16,777,216
  bf16*  WqT  = (bf16*)(ws + 50331648);         //  8,388,608
  bf16*  WkvT = (bf16*)(ws + 58720256);         //  4,194,304
  bf16*  WoT  = (bf16*)(ws + 62914560);         //  8,388,608
  float* bkv  = (float*)(ws + 71303168);        //      4,096
  bf16*  Qb   = (bf16*)(ws + 71307264);         // 16,777,216
  bf16*  KVb  = (bf16*)(ws + 88084480);         //  8,388,608
  bf16*  AO   = Xq;

  const int NEL = 4096 * 2048;
  cvt_bf16_kernel<<<4096, 256, 0, stream>>>(xq, Xq, NEL);
  cvt_bf16_kernel<<<4096, 256, 0, stream>>>(xk, Xk, NEL);
  cvt_bf16_kernel<<<4096, 256, 0, stream>>>(xv, Xv, NEL);
  transpose_cvt_kernel<<<dim3(64, 64), dim3(32, 8), 0, stream>>>(Wq, WqT, 2048, 2048);
  transpose_cvt_kernel<<<dim3(64, 16), dim3(32, 8), 0, stream>>>(Wk, WkvT, 2048, 512);
  transpose_cvt_kernel<<<dim3(64, 16), dim3(32, 8), 0, stream>>>(Wv, WkvT + (size_t)512 * 2048, 2048, 512);
  transpose_cvt_kernel<<<dim3(64, 64), dim3(32, 8), 0, stream>>>(Wo, WoT, 2048, 2048);
  concat_bias_kernel<<<4, 256, 0, stream>>>(bk, bv, bkv);

  // Q projection, pre-scaled by 1/sqrt(512)*log2(e) for exp2-domain softmax
  gemm_bt_bias<bf16><<<dim3(32, 16), 256, 0, stream>>>(Xq, Xq, 1 << 30, WqT, bq, 0.063758717f, Qb, 4096, 2048, 2048);
  // fused K|V projection: N=1024, A switches Xk->Xv at n=512
  gemm_bt_bias<bf16><<<dim3(32, 8), 256, 0, stream>>>(Xk, Xv, 512, WkvT, bkv, 1.0f, KVb, 4096, 1024, 2048);
  // causal GQA attention
  attn_kernel<<<dim3(8, 32, 2), 256, 0, stream>>>(Qb, KVb, AO);
  // output projection -> fp32 out
  gemm_bt_bias<float><<<dim3(32, 16), 256, 0, stream>>>(AO, AO, 1 << 30, WoT, bo, 1.0f, out, 4096, 2048, 2048);
}